// Round 1
// baseline (666.635 us; speedup 1.0000x reference)
//
#include <hip/hip_runtime.h>
#include <math.h>

// Problem constants (fixed shapes from setup_inputs):
//   x [4,2048,4096] f32, W [4096,4096] f32, bias [4096] f32,
//   lora_A [16,4096] f32, lora_B [4096,16] f32, out [8192,4096] f32
#define MDIM 8192
#define NDIM 4096
#define KDIM 4096

typedef __attribute__((ext_vector_type(8))) _Float16 h8;
typedef __attribute__((ext_vector_type(4))) _Float16 h4;
typedef __attribute__((ext_vector_type(4))) float f32x4;

typedef const __attribute__((address_space(1))) void* gas_ptr;
typedef __attribute__((address_space(3))) void* las_ptr;

__device__ inline void load16_to_lds(const void* g, void* l) {
  // async global->LDS, 16B/lane; LDS dest = wave-uniform base + lane*16
  __builtin_amdgcn_global_load_lds((gas_ptr)g, (las_ptr)l, 16, 0, 0);
}

// ---------- 4x4 double helpers ----------
__device__ inline void mm4(const double* A, const double* B, double* C) {
#pragma unroll
  for (int p = 0; p < 4; ++p)
#pragma unroll
    for (int q = 0; q < 4; ++q) {
      double s = 0.0;
#pragma unroll
      for (int r = 0; r < 4; ++r) s += A[p * 4 + r] * B[r * 4 + q];
      C[p * 4 + q] = s;
    }
}
__device__ inline void mm4_bt(const double* A, const double* B, double* C) {
  // C = A * B^T
#pragma unroll
  for (int p = 0; p < 4; ++p)
#pragma unroll
    for (int q = 0; q < 4; ++q) {
      double s = 0.0;
#pragma unroll
      for (int r = 0; r < 4; ++r) s += A[p * 4 + r] * B[q * 4 + r];
      C[p * 4 + q] = s;
    }
}

// ---------- kernel 1: Gu/Gv reductions + factored Newton-Schulz ----------
// One block per head. E[h][p][q] = alpha_h * C5_h[p][q]  (16 floats/head)
__global__ void ns_kernel(const float* __restrict__ lora_A,
                          const float* __restrict__ lora_B,
                          float* __restrict__ E) {
  const int h = blockIdx.x;
  const int tid = threadIdx.x;

  float gu[16], gv[16];
#pragma unroll
  for (int e = 0; e < 16; ++e) { gu[e] = 0.f; gv[e] = 0.f; }

  // Gu[p][q] = sum_o B[o,4h+p]*B[o,4h+q]   (lora_B row-major [4096,16])
  for (int o = tid; o < NDIM; o += 256) {
    const float4 bv = *(const float4*)(lora_B + (size_t)o * 16 + h * 4);
    const float bb[4] = {bv.x, bv.y, bv.z, bv.w};
#pragma unroll
    for (int p = 0; p < 4; ++p)
#pragma unroll
      for (int q = 0; q < 4; ++q) gu[p * 4 + q] += bb[p] * bb[q];
  }
  // Gv[p][q] = sum_i A[4h+p,i]*A[4h+q,i]   (lora_A row-major [16,4096])
  for (int i = tid; i < KDIM; i += 256) {
    float aa[4];
#pragma unroll
    for (int p = 0; p < 4; ++p) aa[p] = lora_A[(size_t)(h * 4 + p) * KDIM + i];
#pragma unroll
    for (int p = 0; p < 4; ++p)
#pragma unroll
      for (int q = 0; q < 4; ++q) gv[p * 4 + q] += aa[p] * aa[q];
  }

  __shared__ float red[256];
  __shared__ float Gu[16], Gv[16];
  for (int e = 0; e < 16; ++e) {
    red[tid] = gu[e];
    __syncthreads();
    for (int s = 128; s > 0; s >>= 1) {
      if (tid < s) red[tid] += red[tid + s];
      __syncthreads();
    }
    if (tid == 0) Gu[e] = red[0];
    __syncthreads();
    red[tid] = gv[e];
    __syncthreads();
    for (int s = 128; s > 0; s >>= 1) {
      if (tid < s) red[tid] += red[tid + s];
      __syncthreads();
    }
    if (tid == 0) Gv[e] = red[0];
    __syncthreads();
  }

  if (tid == 0) {
    double gud[16], gvd[16];
#pragma unroll
    for (int e = 0; e < 16; ++e) { gud[e] = Gu[e]; gvd[e] = Gv[e]; }
    // ||G||_F^2 = tr(Gu*Gv); both symmetric -> elementwise dot
    double tr = 0.0;
#pragma unroll
    for (int e = 0; e < 16; ++e) tr += gud[e] * gvd[e];
    const double alpha = sqrt(tr);
    const double n0 = alpha + 1e-7;

    double C[16] = {0};
    C[0] = C[5] = C[10] = C[15] = 1.0 / n0;  // X0 = U (I/n0) V^T

    const double a = 3.4445, b = -4.775, c = 2.0315;
    for (int it = 0; it < 5; ++it) {
      double T1[16], D[16], DG[16], DGD[16], GuC[16], F[16], Cn[16];
      mm4(C, gvd, T1);      // T1 = C*Gv
      mm4_bt(T1, C, D);     // D  = C*Gv*C^T
      mm4(D, gud, DG);      // DG = D*Gu
      mm4(DG, D, DGD);      // DGD= D*Gu*D
      mm4(gud, C, GuC);     // GuC= Gu*C
#pragma unroll
      for (int e = 0; e < 16; ++e) F[e] = b * D[e] + c * DGD[e];
      mm4(F, GuC, Cn);      // (bD + cDGuD)*Gu*C
#pragma unroll
      for (int e = 0; e < 16; ++e) C[e] = a * C[e] + Cn[e];
    }
#pragma unroll
    for (int e = 0; e < 16; ++e) E[h * 16 + e] = (float)(alpha * C[e]);
  }
}

// ---------- kernel 2: x (f32) -> f16 ----------
__global__ void cvt_x_kernel(const float* __restrict__ x, _Float16* __restrict__ xh) {
  const size_t t = (size_t)blockIdx.x * 256 + threadIdx.x;
  const size_t base = t * 8;
  const float4 a = *(const float4*)(x + base);
  const float4 b = *(const float4*)(x + base + 4);
  h8 o;
  o[0] = (_Float16)a.x; o[1] = (_Float16)a.y; o[2] = (_Float16)a.z; o[3] = (_Float16)a.w;
  o[4] = (_Float16)b.x; o[5] = (_Float16)b.y; o[6] = (_Float16)b.z; o[7] = (_Float16)b.w;
  *(h8*)(xh + base) = o;
}

// ---------- kernel 3: Weff = f16(W + sum_k coef[o][k]*lora_A[k]) ----------
// coef[o][4h+q] = sum_p lora_B[o][4h+p] * E[h][p][q]
__global__ void build_weff_kernel(const float* __restrict__ W,
                                  const float* __restrict__ lora_A,
                                  const float* __restrict__ lora_B,
                                  const float* __restrict__ E,
                                  _Float16* __restrict__ Wh) {
  const int o = blockIdx.x;
  const int tid = threadIdx.x;
  __shared__ float coef[16];
  if (tid < 16) {
    const int h = tid >> 2, q = tid & 3;
    float s = 0.f;
#pragma unroll
    for (int p = 0; p < 4; ++p)
      s += lora_B[(size_t)o * 16 + h * 4 + p] * E[h * 16 + p * 4 + q];
    coef[tid] = s;
  }
  __syncthreads();
  float cf[16];
#pragma unroll
  for (int k = 0; k < 16; ++k) cf[k] = coef[k];

  for (int i = tid * 4; i < KDIM; i += 1024) {
    float4 acc = *(const float4*)(W + (size_t)o * KDIM + i);
#pragma unroll
    for (int k = 0; k < 16; ++k) {
      const float4 av = *(const float4*)(lora_A + (size_t)k * KDIM + i);
      acc.x += cf[k] * av.x; acc.y += cf[k] * av.y;
      acc.z += cf[k] * av.z; acc.w += cf[k] * av.w;
    }
    h4 pk;
    pk[0] = (_Float16)acc.x; pk[1] = (_Float16)acc.y;
    pk[2] = (_Float16)acc.z; pk[3] = (_Float16)acc.w;
    *(h4*)(Wh + (size_t)o * KDIM + i) = pk;
  }
}

// ---------- kernel 4: out[m][n] = sum_k Xh[m][k]*Wh[n][k] + bias[n] ----------
// 128x128 block tile, BK=32, 256 threads = 4 waves, each wave 64x64 (4x4 MFMA tiles)
__launch_bounds__(256, 2)
__global__ void gemm_kernel(const _Float16* __restrict__ Xh,   // [M][K]
                            const _Float16* __restrict__ Wh,   // [N][K]
                            const float* __restrict__ bias,
                            float* __restrict__ out) {         // [M][N]
  __shared__ __align__(16) _Float16 As[128 * 32];  // 8 KB
  __shared__ __align__(16) _Float16 Bs[128 * 32];  // 8 KB

  const int tid = threadIdx.x;
  const int bn = blockIdx.x;  // N/128 = 32
  const int bm = blockIdx.y;  // M/128 = 64
  const int lane = tid & 63;
  const int wave = tid >> 6;
  const int wm = (wave >> 1) * 64;  // wave row offset within tile
  const int wn = (wave & 1) * 64;   // wave col offset within tile
  const int quad = lane >> 4;       // k-chunk selector
  const int r16 = lane & 15;        // row within 16x16 fragment

  // staging: tile is 128 rows x 32 halves = 8192 B; 256 thr x 16 B = 4096 B/round
  const int b0 = tid * 16;              // flat byte offset, round 0
  const int row0 = b0 >> 6;             // 64 B per row
  const int k0e = (b0 & 63) >> 1;       // element offset within row
  const size_t Ar0 = (size_t)(bm * 128 + row0) * KDIM + k0e;
  const size_t Ar1 = (size_t)(bm * 128 + row0 + 64) * KDIM + k0e;
  const size_t Br0 = (size_t)(bn * 128 + row0) * KDIM + k0e;
  const size_t Br1 = (size_t)(bn * 128 + row0 + 64) * KDIM + k0e;

  f32x4 acc[4][4] = {};

  for (int k0 = 0; k0 < KDIM; k0 += 32) {
    __syncthreads();  // previous iteration's LDS reads complete
    load16_to_lds(Xh + Ar0 + k0, (char*)As + b0);
    load16_to_lds(Xh + Ar1 + k0, (char*)As + b0 + 4096);
    load16_to_lds(Wh + Br0 + k0, (char*)Bs + b0);
    load16_to_lds(Wh + Br1 + k0, (char*)Bs + b0 + 4096);
    __syncthreads();  // compiler emits vmcnt(0) drain before barrier

    h8 a[4], b[4];
#pragma unroll
    for (int i = 0; i < 4; ++i) {
      a[i] = *(const h8*)(As + (wm + i * 16 + r16) * 32 + quad * 8);
      b[i] = *(const h8*)(Bs + (wn + i * 16 + r16) * 32 + quad * 8);
    }
#pragma unroll
    for (int i = 0; i < 4; ++i)
#pragma unroll
      for (int j = 0; j < 4; ++j)
        acc[i][j] = __builtin_amdgcn_mfma_f32_16x16x32_f16(a[i], b[j], acc[i][j], 0, 0, 0);
  }

  // epilogue: D row=(lane>>4)*4+reg (M), col=lane&15 (N)
  const int orow = bm * 128 + wm + quad * 4;
  const int ocol = bn * 128 + wn + r16;
#pragma unroll
  for (int j = 0; j < 4; ++j) {
    const int cc = ocol + j * 16;
    const float bv = bias[cc];
#pragma unroll
    for (int i = 0; i < 4; ++i) {
#pragma unroll
      for (int rg = 0; rg < 4; ++rg) {
        const int rr = orow + i * 16 + rg;
        out[(size_t)rr * NDIM + cc] = acc[i][j][rg] + bv;
      }
    }
  }
}

extern "C" void kernel_launch(void* const* d_in, const int* in_sizes, int n_in,
                              void* d_out, int out_size, void* d_ws, size_t ws_size,
                              hipStream_t stream) {
  const float* x      = (const float*)d_in[0];  // [8192,4096]
  const float* W      = (const float*)d_in[1];  // [4096,4096]
  const float* bias   = (const float*)d_in[2];  // [4096]
  const float* lora_A = (const float*)d_in[3];  // [16,4096]
  const float* lora_B = (const float*)d_in[4];  // [4096,16]
  float* out = (float*)d_out;

  char* ws = (char*)d_ws;
  float* E = (float*)ws;                                     // 64 floats
  _Float16* Wh = (_Float16*)(ws + 1024);                     // 4096*4096*2 B
  _Float16* Xh = (_Float16*)(ws + 1024 + (size_t)NDIM * KDIM * 2);  // 8192*4096*2 B

  ns_kernel<<<dim3(4), dim3(256), 0, stream>>>(lora_A, lora_B, E);
  cvt_x_kernel<<<dim3((MDIM * KDIM) / (256 * 8)), dim3(256), 0, stream>>>(x, Xh);
  build_weff_kernel<<<dim3(NDIM), dim3(256), 0, stream>>>(W, lora_A, lora_B, E, Wh);
  gemm_kernel<<<dim3(NDIM / 128, MDIM / 128), dim3(256), 0, stream>>>(Xh, Wh, bias, out);
}

// Round 2
// 645.749 us; speedup vs baseline: 1.0323x; 1.0323x over previous
//
#include <hip/hip_runtime.h>
#include <math.h>

// Problem constants (fixed shapes from setup_inputs):
//   x [4,2048,4096] f32, W [4096,4096] f32, bias [4096] f32,
//   lora_A [16,4096] f32, lora_B [4096,16] f32, out [8192,4096] f32
#define MDIM 8192
#define NDIM 4096
#define KDIM 4096

typedef __attribute__((ext_vector_type(8))) _Float16 h8;
typedef __attribute__((ext_vector_type(4))) _Float16 h4;
typedef __attribute__((ext_vector_type(4))) float f32x4;

typedef const __attribute__((address_space(1))) void* gas_ptr;
typedef __attribute__((address_space(3))) void* las_ptr;

__device__ inline void load16_to_lds(const void* g, void* l) {
  // async global->LDS, 16B/lane; LDS dest = wave-uniform base + lane*16
  __builtin_amdgcn_global_load_lds((gas_ptr)g, (las_ptr)l, 16, 0, 0);
}

// ---------- 4x4 double helpers ----------
__device__ inline void mm4(const double* A, const double* B, double* C) {
#pragma unroll
  for (int p = 0; p < 4; ++p)
#pragma unroll
    for (int q = 0; q < 4; ++q) {
      double s = 0.0;
#pragma unroll
      for (int r = 0; r < 4; ++r) s += A[p * 4 + r] * B[r * 4 + q];
      C[p * 4 + q] = s;
    }
}
__device__ inline void mm4_bt(const double* A, const double* B, double* C) {
  // C = A * B^T
#pragma unroll
  for (int p = 0; p < 4; ++p)
#pragma unroll
    for (int q = 0; q < 4; ++q) {
      double s = 0.0;
#pragma unroll
      for (int r = 0; r < 4; ++r) s += A[p * 4 + r] * B[q * 4 + r];
      C[p * 4 + q] = s;
    }
}

// ---------- kernel 1: Gu/Gv reductions + factored Newton-Schulz ----------
// One block per head. E[h][p][q] = alpha_h * C5_h[p][q]  (16 floats/head)
__global__ void ns_kernel(const float* __restrict__ lora_A,
                          const float* __restrict__ lora_B,
                          float* __restrict__ E) {
  const int h = blockIdx.x;
  const int tid = threadIdx.x;
  const int lane = tid & 63;
  const int wave = tid >> 6;

  float gu[16], gv[16];
#pragma unroll
  for (int e = 0; e < 16; ++e) { gu[e] = 0.f; gv[e] = 0.f; }

  // Gu[p][q] = sum_o B[o,4h+p]*B[o,4h+q]   (lora_B row-major [4096,16])
  for (int o = tid; o < NDIM; o += 256) {
    const float4 bv = *(const float4*)(lora_B + (size_t)o * 16 + h * 4);
    const float bb[4] = {bv.x, bv.y, bv.z, bv.w};
#pragma unroll
    for (int p = 0; p < 4; ++p)
#pragma unroll
      for (int q = 0; q < 4; ++q) gu[p * 4 + q] += bb[p] * bb[q];
  }
  // Gv[p][q] = sum_i A[4h+p,i]*A[4h+q,i]   (lora_A row-major [16,4096])
  for (int i = tid; i < KDIM; i += 256) {
    float aa[4];
#pragma unroll
    for (int p = 0; p < 4; ++p) aa[p] = lora_A[(size_t)(h * 4 + p) * KDIM + i];
#pragma unroll
    for (int p = 0; p < 4; ++p)
#pragma unroll
      for (int q = 0; q < 4; ++q) gv[p * 4 + q] += aa[p] * aa[q];
  }

  // wave-level butterfly reduction (64 lanes), then 4 partials per element in LDS
#pragma unroll
  for (int e = 0; e < 16; ++e) {
#pragma unroll
    for (int off = 32; off > 0; off >>= 1) {
      gu[e] += __shfl_down(gu[e], off, 64);
      gv[e] += __shfl_down(gv[e], off, 64);
    }
  }
  __shared__ float pu[4][16], pv[4][16];
  if (lane == 0) {
#pragma unroll
    for (int e = 0; e < 16; ++e) { pu[wave][e] = gu[e]; pv[wave][e] = gv[e]; }
  }
  __syncthreads();

  if (tid == 0) {
    double gud[16], gvd[16];
#pragma unroll
    for (int e = 0; e < 16; ++e) {
      gud[e] = (double)pu[0][e] + pu[1][e] + pu[2][e] + pu[3][e];
      gvd[e] = (double)pv[0][e] + pv[1][e] + pv[2][e] + pv[3][e];
    }
    // ||G||_F^2 = tr(Gu*Gv); both symmetric -> elementwise dot
    double tr = 0.0;
#pragma unroll
    for (int e = 0; e < 16; ++e) tr += gud[e] * gvd[e];
    const double alpha = sqrt(tr);
    const double n0 = alpha + 1e-7;

    double C[16] = {0};
    C[0] = C[5] = C[10] = C[15] = 1.0 / n0;  // X0 = U (I/n0) V^T

    const double a = 3.4445, b = -4.775, c = 2.0315;
    for (int it = 0; it < 5; ++it) {
      double T1[16], D[16], DG[16], DGD[16], GuC[16], F[16], Cn[16];
      mm4(C, gvd, T1);      // T1 = C*Gv
      mm4_bt(T1, C, D);     // D  = C*Gv*C^T
      mm4(D, gud, DG);      // DG = D*Gu
      mm4(DG, D, DGD);      // DGD= D*Gu*D
      mm4(gud, C, GuC);     // GuC= Gu*C
#pragma unroll
      for (int e = 0; e < 16; ++e) F[e] = b * D[e] + c * DGD[e];
      mm4(F, GuC, Cn);      // (bD + cDGuD)*Gu*C
#pragma unroll
      for (int e = 0; e < 16; ++e) C[e] = a * C[e] + Cn[e];
    }
#pragma unroll
    for (int e = 0; e < 16; ++e) E[h * 16 + e] = (float)(alpha * C[e]);
  }
}

// ---------- kernel 2 (fused): blocks [0,4096) build Weff; [4096,20480) cast x ----------
// Weff = f16(W + sum_k coef[o][k]*lora_A[k]),  coef[o][4h+q] = sum_p lora_B[o][4h+p]*E[h][p][q]
__global__ void prep_kernel(const float* __restrict__ x,
                            const float* __restrict__ W,
                            const float* __restrict__ lora_A,
                            const float* __restrict__ lora_B,
                            const float* __restrict__ E,
                            _Float16* __restrict__ Wh,
                            _Float16* __restrict__ Xh) {
  const int tid = threadIdx.x;
  if (blockIdx.x < NDIM) {
    const int o = blockIdx.x;
    __shared__ float coef[16];
    if (tid < 16) {
      const int h = tid >> 2, q = tid & 3;
      float s = 0.f;
#pragma unroll
      for (int p = 0; p < 4; ++p)
        s += lora_B[(size_t)o * 16 + h * 4 + p] * E[h * 16 + p * 4 + q];
      coef[tid] = s;
    }
    __syncthreads();
    float cf[16];
#pragma unroll
    for (int k = 0; k < 16; ++k) cf[k] = coef[k];

    for (int i = tid * 4; i < KDIM; i += 1024) {
      float4 acc = *(const float4*)(W + (size_t)o * KDIM + i);
#pragma unroll
      for (int k = 0; k < 16; ++k) {
        const float4 av = *(const float4*)(lora_A + (size_t)k * KDIM + i);
        acc.x += cf[k] * av.x; acc.y += cf[k] * av.y;
        acc.z += cf[k] * av.z; acc.w += cf[k] * av.w;
      }
      h4 pk;
      pk[0] = (_Float16)acc.x; pk[1] = (_Float16)acc.y;
      pk[2] = (_Float16)acc.z; pk[3] = (_Float16)acc.w;
      *(h4*)(Wh + (size_t)o * KDIM + i) = pk;
    }
  } else {
    const size_t t = (size_t)(blockIdx.x - NDIM) * 256 + tid;
    const size_t base = t * 8;
    const float4 a = *(const float4*)(x + base);
    const float4 b = *(const float4*)(x + base + 4);
    h8 o;
    o[0] = (_Float16)a.x; o[1] = (_Float16)a.y; o[2] = (_Float16)a.z; o[3] = (_Float16)a.w;
    o[4] = (_Float16)b.x; o[5] = (_Float16)b.y; o[6] = (_Float16)b.z; o[7] = (_Float16)b.w;
    *(h8*)(Xh + base) = o;
  }
}

// ---------- kernel 3: out[m][n] = sum_k Xh[m][k]*Wh[n][k] + bias[n] ----------
// 128x128 block tile, BK=32, 256 threads = 4 waves, each wave 64x64 (4x4 MFMA tiles).
// LDS bank-conflict fix: XOR swizzle of the 16B k-chunks within each row, done on the
// GLOBAL source side of global_load_lds (LDS dest must stay contiguous at lane*16).
// Physical slot (row, q) holds global chunk (row, q ^ ((row>>1)&3)); the reader's
// 16-lane quad then touches 4 banks x 2-way (free) instead of 2 banks x 8-way.
__launch_bounds__(256, 2)
__global__ void gemm_kernel(const _Float16* __restrict__ Xh,   // [M][K]
                            const _Float16* __restrict__ Wh,   // [N][K]
                            const float* __restrict__ bias,
                            float* __restrict__ out) {         // [M][N]
  __shared__ __align__(16) _Float16 As[128 * 32];  // 8 KB
  __shared__ __align__(16) _Float16 Bs[128 * 32];  // 8 KB

  const int tid = threadIdx.x;
  const int bn = blockIdx.x;  // N/128 = 32
  const int bm = blockIdx.y;  // M/128 = 64
  const int lane = tid & 63;
  const int wave = tid >> 6;
  const int wm = (wave >> 1) * 64;  // wave row offset within tile
  const int wn = (wave & 1) * 64;   // wave col offset within tile
  const int quad = lane >> 4;       // k-chunk selector
  const int r16 = lane & 15;        // row within 16x16 fragment

  // staging: tile is 128 rows x 4 chunks of 16B; round r covers chunks [r*256, r*256+256)
  // chunk c: row = c>>2, slot q = c&3, global column-chunk = q ^ ((row>>1)&3)
  const int c0 = tid;                  // round 0
  const int c1 = tid + 256;            // round 1
  const int row0 = c0 >> 2, row1 = c1 >> 2;
  const int col0 = ((c0 & 3) ^ ((row0 >> 1) & 3)) * 8;  // element offset in row
  const int col1 = ((c1 & 3) ^ ((row1 >> 1) & 3)) * 8;
  const size_t Ar0 = (size_t)(bm * 128 + row0) * KDIM + col0;
  const size_t Ar1 = (size_t)(bm * 128 + row1) * KDIM + col1;
  const size_t Br0 = (size_t)(bn * 128 + row0) * KDIM + col0;
  const size_t Br1 = (size_t)(bn * 128 + row1) * KDIM + col1;
  const int ldsb = tid * 16;  // LDS byte offset for this thread's chunk, both rounds

  f32x4 acc[4][4] = {};

  for (int k0 = 0; k0 < KDIM; k0 += 32) {
    __syncthreads();  // previous iteration's LDS reads complete
    load16_to_lds(Xh + Ar0 + k0, (char*)As + ldsb);
    load16_to_lds(Xh + Ar1 + k0, (char*)As + ldsb + 4096);
    load16_to_lds(Wh + Br0 + k0, (char*)Bs + ldsb);
    load16_to_lds(Wh + Br1 + k0, (char*)Bs + ldsb + 4096);
    __syncthreads();  // compiler emits vmcnt(0) drain before barrier

    h8 a[4], b[4];
#pragma unroll
    for (int i = 0; i < 4; ++i) {
      const int ra = wm + i * 16 + r16;
      const int rb = wn + i * 16 + r16;
      a[i] = *(const h8*)(As + ra * 32 + ((quad ^ ((ra >> 1) & 3)) * 8));
      b[i] = *(const h8*)(Bs + rb * 32 + ((quad ^ ((rb >> 1) & 3)) * 8));
    }
#pragma unroll
    for (int i = 0; i < 4; ++i)
#pragma unroll
      for (int j = 0; j < 4; ++j)
        acc[i][j] = __builtin_amdgcn_mfma_f32_16x16x32_f16(a[i], b[j], acc[i][j], 0, 0, 0);
  }

  // epilogue: D row=(lane>>4)*4+reg (M), col=lane&15 (N)
  const int orow = bm * 128 + wm + quad * 4;
  const int ocol = bn * 128 + wn + r16;
#pragma unroll
  for (int j = 0; j < 4; ++j) {
    const int cc = ocol + j * 16;
    const float bv = bias[cc];
#pragma unroll
    for (int i = 0; i < 4; ++i) {
#pragma unroll
      for (int rg = 0; rg < 4; ++rg) {
        const int rr = orow + i * 16 + rg;
        out[(size_t)rr * NDIM + cc] = acc[i][j][rg] + bv;
      }
    }
  }
}

extern "C" void kernel_launch(void* const* d_in, const int* in_sizes, int n_in,
                              void* d_out, int out_size, void* d_ws, size_t ws_size,
                              hipStream_t stream) {
  const float* x      = (const float*)d_in[0];  // [8192,4096]
  const float* W      = (const float*)d_in[1];  // [4096,4096]
  const float* bias   = (const float*)d_in[2];  // [4096]
  const float* lora_A = (const float*)d_in[3];  // [16,4096]
  const float* lora_B = (const float*)d_in[4];  // [4096,16]
  float* out = (float*)d_out;

  char* ws = (char*)d_ws;
  float* E = (float*)ws;                                     // 64 floats
  _Float16* Wh = (_Float16*)(ws + 1024);                     // 4096*4096*2 B
  _Float16* Xh = (_Float16*)(ws + 1024 + (size_t)NDIM * KDIM * 2);  // 8192*4096*2 B

  ns_kernel<<<dim3(4), dim3(256), 0, stream>>>(lora_A, lora_B, E);
  prep_kernel<<<dim3(NDIM + (MDIM * KDIM) / (256 * 8)), dim3(256), 0, stream>>>(
      x, W, lora_A, lora_B, E, Wh, Xh);
  gemm_kernel<<<dim3(NDIM / 128, MDIM / 128), dim3(256), 0, stream>>>(Xh, Wh, bias, out);
}